// Round 4
// baseline (167.978 us; speedup 1.0000x reference)
//
#include <hip/hip_runtime.h>
#include <hip/hip_bf16.h>
#include <hip/hip_cooperative_groups.h>
#include <math.h>

namespace cg = cooperative_groups;

#define Bn  16
#define Ln  256
#define Wn  4
#define Hn  128
#define Nn  259          // L + W - 1
#define EPSF 1e-6f
#define NB  (Bn * Nn)    // 4144
#define GRIDB 512        // 2 blocks/CU -> cooperative co-residency guaranteed

typedef float f32x4 __attribute__((ext_vector_type(4)));
typedef short s16x8 __attribute__((ext_vector_type(8)));

// ws layout: x1a[NB] | x2a[NB] | n1[NB] | n2[NB]  (floats)
//            xb1[NB*Hn] | xb2[NB*Hn]              (bf16 as ushort)

__global__ __launch_bounds__(256, 2) void fused(const float* __restrict__ x1,
                                                const float* __restrict__ x2,
                                                float* __restrict__ ws,
                                                float* __restrict__ out) {
    __shared__ unsigned short As[64 * 136];   // stride 136 -> 2-way bank alias (free)
    __shared__ unsigned short Bs[64 * 136];
    __shared__ float n2s[64], n1s[64];

    float*       x1a = ws;
    float*       x2a = ws + NB;
    const float* n1g = ws + 2 * NB;
    const float* n2g = ws + 3 * NB;
    unsigned short* xb1 = (unsigned short*)(ws + 4 * NB);
    unsigned short* xb2 = xb1 + (size_t)NB * Hn;

    const int tid  = threadIdx.x;
    const int lane = tid & 63;

    // ---- phase 1: bf16 convert rows + ||row||^2 norms + zero accumulators ----
    // wave-per-row, grid-stride over 2*NB rows (2048 waves, ~4 rows each)
    const int wave0 = (blockIdx.x << 2) | (tid >> 6);
    for (int wid = wave0; wid < 2 * NB; wid += GRIDB * 4) {
        const bool one = (wid < NB);
        const float* x = one ? x1 : x2;
        const int    r = one ? wid : wid - NB;
        const float2 v = ((const float2*)(x + (size_t)r * Hn))[lane];
        union { __hip_bfloat16 h; unsigned short u; } c0, c1;
        c0.h = __float2bfloat16(v.x);
        c1.h = __float2bfloat16(v.y);
        unsigned short* xb = one ? xb1 : xb2;
        ((unsigned int*)(xb + (size_t)r * Hn))[lane] =
            (unsigned int)c0.u | ((unsigned int)c1.u << 16);
        const float a0 = __bfloat162float(c0.h), a1 = __bfloat162float(c1.h);
        float s = a0 * a0 + a1 * a1;
        #pragma unroll
        for (int off = 32; off; off >>= 1) s += __shfl_down(s, off);
        if (lane == 0) {
            ws[wid]          = 0.f;   // zero x1a / x2a slot
            ws[2 * NB + wid] = s;     // n1 / n2 (bf16-rounded values)
        }
    }

    cg::this_grid().sync();

    // ---- phase 2: 64x64 att tile per block via bf16 MFMA 16x16x32 ----
    // A-frag: lane holds A[m=lane&15][k=(lane>>4)*8+0..7]; C/D: col=lane&15,
    // row=(lane>>4)*4+reg  (HW-verified layouts, learn_hip m89/m91/m120)
    if (blockIdx.x < 400) {
        const int b   = blockIdx.x / 25;
        const int rem = blockIdx.x % 25;
        const int i0  = (rem / 5) * 64;
        const int j0  = (rem % 5) * 64;

        for (int idx = tid; idx < 1024; idx += 256) {
            const int r = idx >> 4, c = idx & 15;
            uint4 va = make_uint4(0, 0, 0, 0), vb = va;
            if (i0 + r < Nn) va = ((const uint4*)(xb2 + (size_t)(b * Nn + i0 + r) * Hn))[c];
            if (j0 + r < Nn) vb = ((const uint4*)(xb1 + (size_t)(b * Nn + j0 + r) * Hn))[c];
            *((uint4*)&As[r * 136 + c * 8]) = va;
            *((uint4*)&Bs[r * 136 + c * 8]) = vb;
        }
        if (tid < 64)       n2s[tid]      = (i0 + tid < Nn)        ? n2g[b * Nn + i0 + tid]        : 0.f;
        else if (tid < 128) n1s[tid - 64] = (j0 + (tid - 64) < Nn) ? n1g[b * Nn + j0 + (tid - 64)] : 0.f;
        __syncthreads();

        const int w = tid >> 6, rsel = lane & 15, q = lane >> 4;

        f32x4 acc[4] = {{0,0,0,0}, {0,0,0,0}, {0,0,0,0}, {0,0,0,0}};
        const unsigned short* arow = &As[(w * 16 + rsel) * 136 + q * 8];
        const unsigned short* brow = &Bs[rsel * 136 + q * 8];
        #pragma unroll
        for (int s = 0; s < 4; ++s) {               // K-steps of 32
            const s16x8 af = *((const s16x8*)(arow + s * 32));
            #pragma unroll
            for (int t = 0; t < 4; ++t) {           // j-tiles of 16
                const s16x8 bf = *((const s16x8*)(brow + t * 16 * 136 + s * 32));
                acc[t] = __builtin_amdgcn_mfma_f32_16x16x32_bf16(af, bf, acc[t], 0, 0, 0);
            }
        }

        float rowacc[4] = {0.f, 0.f, 0.f, 0.f};
        #pragma unroll
        for (int t = 0; t < 4; ++t) {
            const int   j   = j0 + t * 16 + rsel;
            const bool  jv  = (j < Nn);
            const float n1v = n1s[t * 16 + rsel];
            float cp = 0.f;
            #pragma unroll
            for (int reg = 0; reg < 4; ++reg) {
                const int   i   = i0 + w * 16 + q * 4 + reg;
                const float e   = fmaf(-2.f, acc[t][reg], n2s[w * 16 + q * 4 + reg] + n1v + EPSF);
                const float att = ((i < Nn) && jv) ? 1.f / (sqrtf(e) + 1.f) : 0.f;
                rowacc[reg] += att;
                cp          += att;
            }
            cp += __shfl_xor(cp, 16);
            cp += __shfl_xor(cp, 32);
            if (q == 0 && jv) atomicAdd(&x1a[b * Nn + j], cp);
        }
        #pragma unroll
        for (int reg = 0; reg < 4; ++reg) {
            float rs = rowacc[reg];
            #pragma unroll
            for (int off = 8; off; off >>= 1) rs += __shfl_down(rs, off, 16);
            const int i = i0 + w * 16 + q * 4 + reg;
            if (rsel == 0 && i < Nn) atomicAdd(&x2a[b * Nn + i], rs);
        }
    }

    cg::this_grid().sync();

    // ---- phase 3: wp -- out[b,l,h] = sum_{k<4} x[b,l+k,h]*a[b,l+k] ----
    const int PER = Bn * Ln * Hn / 4;    // 131072 float4 per output
    for (int g = blockIdx.x * 256 + tid; g < 2 * PER; g += GRIDB * 256) {
        const float* x; const float* a; float4* o; int e;
        if (g < PER) { x = x1; a = x1a; o = (float4*)out;       e = g; }
        else         { x = x2; a = x2a; o = (float4*)out + PER; e = g - PER; }

        const int b   = e >> 13;
        const int rem = e & 8191;
        const int l   = rem >> 5;
        const int h4  = rem & 31;

        const float4* xb = (const float4*)(x + (size_t)b * Nn * Hn);
        float4 accv = make_float4(0.f, 0.f, 0.f, 0.f);
        #pragma unroll
        for (int k = 0; k < Wn; ++k) {
            const float  av = a[b * Nn + l + k];
            const float4 xv = xb[(l + k) * (Hn / 4) + h4];
            accv.x += av * xv.x;
            accv.y += av * xv.y;
            accv.z += av * xv.z;
            accv.w += av * xv.w;
        }
        o[e] = accv;
    }
}

extern "C" void kernel_launch(void* const* d_in, const int* in_sizes, int n_in,
                              void* d_out, int out_size, void* d_ws, size_t ws_size,
                              hipStream_t stream) {
    const float* x1 = (const float*)d_in[0];
    const float* x2 = (const float*)d_in[1];
    float* ws   = (float*)d_ws;
    float* outp = (float*)d_out;

    void* args[] = { (void*)&x1, (void*)&x2, (void*)&ws, (void*)&outp };
    hipLaunchCooperativeKernel((const void*)fused, dim3(GRIDB), dim3(256),
                               args, 0, stream);
}

// Round 5
// 70.172 us; speedup vs baseline: 2.3938x; 2.3938x over previous
//
#include <hip/hip_runtime.h>
#include <hip/hip_bf16.h>
#include <math.h>

#define Bn  16
#define Ln  256
#define Wn  4
#define Hn  128
#define Nn  259          // L + W - 1
#define EPSF 1e-6f
#define PSTR 320         // padded per-(slice,batch) stride in partial arrays
#define X2AP_OFF (5 * Bn * PSTR)      // x1a_p size in floats

typedef float f32x4 __attribute__((ext_vector_type(4)));
typedef short s16x8 __attribute__((ext_vector_type(8)));

__device__ __forceinline__ unsigned short bfb(float x) {
    union { __hip_bfloat16 h; unsigned short u; } t;
    t.h = __float2bfloat16(x);
    return t.u;
}

// Block: 64i x 64j att tile, batch b. fp32 -> bf16 conversion fused into LDS
// staging; row norms via mfma(a,a) Gram diagonal (no prep kernel, no atomics).
// Partial sums to private slices:
//   x1a_p[it][b][j] = sum over this block's 64 i   (5 it slices)
//   x2a_p[jt][b][i] = sum over this block's 64 j   (5 jt slices)
// A-frag: lane holds A[m=lane&15][k=(lane>>4)*8+j]; C/D: col=lane&15,
// row=(lane>>4)*4+reg  (HW-verified, learn_hip m89/m91/m120).
__global__ __launch_bounds__(256) void att2(const float* __restrict__ x1,
                                            const float* __restrict__ x2,
                                            float* __restrict__ ws) {
    __shared__ unsigned short As[64 * 136];   // x2 rows; stride 136 -> 2-way banks (free)
    __shared__ unsigned short Bs[64 * 136];   // x1 rows
    __shared__ float n2s[64], n1s[64];
    __shared__ float colpart[4 * 64];

    const int it = blockIdx.x, jt = blockIdx.y, b = blockIdx.z;
    const int i0 = it * 64, j0 = jt * 64;
    const int tid = threadIdx.x;

    const float* __restrict__ x1b = x1 + (size_t)b * Nn * Hn;
    const float* __restrict__ x2b = x2 + (size_t)b * Nn * Hn;

    // stage both tiles: 8 iters x (one float4 per lane per tile), convert to bf16
    #pragma unroll
    for (int iter = 0; iter < 8; ++iter) {
        const int idx = iter * 256 + tid;
        const int r = idx >> 5, c4 = idx & 31;
        float4 va = make_float4(0.f, 0.f, 0.f, 0.f), vb = va;
        if (i0 + r < Nn) va = ((const float4*)(x2b + (i0 + r) * Hn))[c4];
        if (j0 + r < Nn) vb = ((const float4*)(x1b + (j0 + r) * Hn))[c4];
        const unsigned long long pa =
            (unsigned long long)bfb(va.x)        | ((unsigned long long)bfb(va.y) << 16) |
            ((unsigned long long)bfb(va.z) << 32) | ((unsigned long long)bfb(va.w) << 48);
        const unsigned long long pb =
            (unsigned long long)bfb(vb.x)        | ((unsigned long long)bfb(vb.y) << 16) |
            ((unsigned long long)bfb(vb.z) << 32) | ((unsigned long long)bfb(vb.w) << 48);
        *((unsigned long long*)&As[r * 136 + c4 * 4]) = pa;
        *((unsigned long long*)&Bs[r * 136 + c4 * 4]) = pb;
    }
    __syncthreads();

    const int w = tid >> 6, lane = tid & 63;
    const int rsel = lane & 15, q = lane >> 4;

    f32x4 acc[4] = {{0,0,0,0}, {0,0,0,0}, {0,0,0,0}, {0,0,0,0}};
    f32x4 accA = {0,0,0,0}, accB = {0,0,0,0};     // Gram accumulators for norms
    const unsigned short* arow  = &As[(w * 16 + rsel) * 136 + q * 8];
    const unsigned short* bnrow = &Bs[(w * 16 + rsel) * 136 + q * 8];
    const unsigned short* brow  = &Bs[rsel * 136 + q * 8];
    #pragma unroll
    for (int s = 0; s < 4; ++s) {                 // K-steps of 32
        const s16x8 af = *((const s16x8*)(arow + s * 32));
        const s16x8 bn = *((const s16x8*)(bnrow + s * 32));
        accA = __builtin_amdgcn_mfma_f32_16x16x32_bf16(af, af, accA, 0, 0, 0);
        accB = __builtin_amdgcn_mfma_f32_16x16x32_bf16(bn, bn, accB, 0, 0, 0);
        #pragma unroll
        for (int t = 0; t < 4; ++t) {             // j-tiles of 16
            const s16x8 bf = *((const s16x8*)(brow + t * 16 * 136 + s * 32));
            acc[t] = __builtin_amdgcn_mfma_f32_16x16x32_bf16(af, bf, acc[t], 0, 0, 0);
        }
    }

    // Gram diagonal d lives at lane(col=d, row=d): q==d>>2, reg==d&3
    if (q == (rsel >> 2)) {
        n2s[w * 16 + rsel] = accA[rsel & 3];
        n1s[w * 16 + rsel] = accB[rsel & 3];
    }
    __syncthreads();   // n1s is read across waves below

    float rowacc[4] = {0.f, 0.f, 0.f, 0.f};
    #pragma unroll
    for (int t = 0; t < 4; ++t) {
        const int   j   = j0 + t * 16 + rsel;
        const bool  jv  = (j < Nn);
        const float n1v = n1s[t * 16 + rsel];
        float cp = 0.f;
        #pragma unroll
        for (int reg = 0; reg < 4; ++reg) {
            const int   i   = i0 + w * 16 + q * 4 + reg;
            const float e   = fmaf(-2.f, acc[t][reg], n2s[w * 16 + q * 4 + reg] + n1v + EPSF);
            const float att = ((i < Nn) && jv) ? 1.f / (sqrtf(e) + 1.f) : 0.f;
            rowacc[reg] += att;
            cp          += att;
        }
        cp += __shfl_xor(cp, 16);                 // reduce over q (wave's 16 i)
        cp += __shfl_xor(cp, 32);
        if (q == 0) colpart[w * 64 + t * 16 + rsel] = cp;
    }
    // row sums (this block's 64 j): each i owned by exactly one wave -> plain store
    #pragma unroll
    for (int reg = 0; reg < 4; ++reg) {
        float rs = rowacc[reg];
        #pragma unroll
        for (int off = 8; off; off >>= 1) rs += __shfl_down(rs, off, 16);
        const int i = i0 + w * 16 + q * 4 + reg;
        if (rsel == 0 && i < Nn)
            ws[X2AP_OFF + (jt * Bn + b) * PSTR + i] = rs;
    }
    __syncthreads();   // colpart complete
    if (tid < 64) {
        const int j = j0 + tid;
        if (j < Nn)
            ws[(it * Bn + b) * PSTR + j] =
                colpart[tid] + colpart[64 + tid] + colpart[128 + tid] + colpart[192 + tid];
    }
}

// out[b,l,h] = sum_{k<4} x[b,l+k,h] * a[b,l+k], a = sum of 5 partial slices.
// Block covers 256 consecutive float4 = 8 l values of one (half,b); needs
// a[b, l0..l0+10] -> reduce the 5 partials once into LDS.
__global__ __launch_bounds__(256) void wp_kernel(const float* __restrict__ x1,
                                                 const float* __restrict__ x2,
                                                 const float* __restrict__ ws,
                                                 float* __restrict__ out) {
    __shared__ float a_s[11];
    const int PER = Bn * Ln * Hn / 4;    // 131072 float4 per output
    const int blk = blockIdx.x;
    const bool second = blk >= 512;
    const int eb = (second ? blk - 512 : blk) * 256;
    const int b  = eb >> 13;
    const int l0 = (eb & 8191) >> 5;

    const float* x = second ? x2 : x1;
    const float* p = ws + (second ? X2AP_OFF : 0) + b * PSTR;
    if (threadIdx.x < 11) {
        const int j = l0 + threadIdx.x;          // <= 258, always written
        float s = 0.f;
        #pragma unroll
        for (int t = 0; t < 5; ++t) s += p[t * (Bn * PSTR) + j];
        a_s[threadIdx.x] = s;
    }
    __syncthreads();

    const int e  = eb + threadIdx.x;
    const int l  = (e & 8191) >> 5;
    const int h4 = e & 31;
    const float4* xb = (const float4*)(x + (size_t)b * Nn * Hn);
    float4 acc = make_float4(0.f, 0.f, 0.f, 0.f);
    #pragma unroll
    for (int k = 0; k < Wn; ++k) {
        const float  av = a_s[l - l0 + k];
        const float4 xv = xb[(l + k) * (Hn / 4) + h4];
        acc.x += av * xv.x;
        acc.y += av * xv.y;
        acc.z += av * xv.z;
        acc.w += av * xv.w;
    }
    ((float4*)out)[(second ? PER : 0) + e] = acc;
}

extern "C" void kernel_launch(void* const* d_in, const int* in_sizes, int n_in,
                              void* d_out, int out_size, void* d_ws, size_t ws_size,
                              hipStream_t stream) {
    const float* x1 = (const float*)d_in[0];
    const float* x2 = (const float*)d_in[1];
    float* ws = (float*)d_ws;

    dim3 gridA(5, 5, Bn);                 // 64x64 tiles over 259x259, 16 batches
    att2<<<gridA, 256, 0, stream>>>(x1, x2, ws);

    wp_kernel<<<1024, 256, 0, stream>>>(x1, x2, ws, (float*)d_out);
}